// Round 1
// baseline (267.590 us; speedup 1.0000x reference)
//
#include <hip/hip_runtime.h>
#include <hip/hip_bf16.h>

#define B_ 32
#define C_ 128
#define H_ 96
#define W_ 96
#define Z_ 64

typedef __bf16 bf16x8 __attribute__((ext_vector_type(8)));
typedef float f32x4 __attribute__((ext_vector_type(4)));

// ---------- prep_x: f32 NCHW -> bf16 NHWC ----------
__global__ __launch_bounds__(256) void prep_x_kernel(const float* __restrict__ x,
                                                     __hip_bfloat16* __restrict__ xn) {
  __shared__ float tile[32][97];
  int icg = blockIdx.x;              // 0..3  (32-channel group)
  int h   = blockIdx.y;              // 0..95
  int b   = blockIdx.z;              // 0..31
  const float* src = x + ((size_t)(b * C_ + icg * 32) * H_ + h) * W_;
  for (int idx = threadIdx.x; idx < 32 * 96; idx += 256) {
    int ic = idx / 96, w = idx - ic * 96;
    tile[ic][w] = src[(size_t)ic * (H_ * W_) + w];
  }
  __syncthreads();
  __hip_bfloat16* dst = xn + ((size_t)(b * H_ + h) * W_) * C_ + icg * 32;
  for (int idx = threadIdx.x; idx < 96 * 32; idx += 256) {
    int w = idx >> 5, ic = idx & 31;
    dst[(size_t)w * C_ + ic] = __float2bfloat16(tile[ic][w]);
  }
}

// ---------- prep_gpd: gate/pw/dw projections of z ----------
__global__ __launch_bounds__(256) void prep_gpd_kernel(
    const float* __restrict__ z, const float* __restrict__ gw,
    const float* __restrict__ pww, const float* __restrict__ dww,
    float* __restrict__ gate, float* __restrict__ pwv, float* __restrict__ dwv) {
  __shared__ float zs[B_ * Z_];
  for (int i = threadIdx.x; i < B_ * Z_; i += 256) zs[i] = z[i];
  __syncthreads();
  int j = blockIdx.x * 256 + threadIdx.x;   // 0..17663
  const float* wrow; float* outp; int stride;
  if (j < 16384)            { wrow = pww + (size_t)j * 64;            outp = pwv + j;           stride = 16384; }
  else if (j < 16384 + 1152){ int jj = j - 16384; wrow = dww + (size_t)jj * 64; outp = dwv + jj; stride = 1152; }
  else                      { int jj = j - 17536; wrow = gw  + (size_t)jj * 64; outp = gate + jj; stride = 128; }
  float wr[64];
  #pragma unroll
  for (int i = 0; i < 16; i++) {
    float4 v = ((const float4*)wrow)[i];
    wr[4*i] = v.x; wr[4*i+1] = v.y; wr[4*i+2] = v.z; wr[4*i+3] = v.w;
  }
  for (int b = 0; b < B_; b++) {
    float acc = 0.f;
    #pragma unroll
    for (int i = 0; i < 64; i++) acc += zs[b * 64 + i] * wr[i];
    outp[(size_t)b * stride] = acc;
  }
}

// ---------- prep_w: merged weights -> Wt[b][tap][oc][ic] bf16 ----------
__global__ __launch_bounds__(256) void prep_w_kernel(
    const float* __restrict__ base, const float* __restrict__ gate,
    const float* __restrict__ pwv, const float* __restrict__ dwv,
    __hip_bfloat16* __restrict__ Wt) {
  int gid = blockIdx.x * 256 + threadIdx.x;   // one thread = 2 consecutive ic
  int ic2  = gid & 63;  int rest  = gid >> 6;
  int oc   = rest & 127; int rest2 = rest >> 7;
  int t = rest2 % 9; int b = rest2 / 9;
  int ic = ic2 * 2;
  float g = gate[b * 128 + oc];
  float d = dwv[b * 1152 + oc * 9 + t];
  const float* pwp = pwv + (size_t)b * 16384 + oc * 128 + ic;
  const float* bp  = base + ((size_t)(oc * 128 + ic)) * 9 + t;
  float w0 = bp[0] * g + pwp[0] * d;
  float w1 = bp[9] * g + pwp[1] * d;
  __hip_bfloat16* o = Wt + (size_t)gid * 2;
  o[0] = __float2bfloat16(w0);
  o[1] = __float2bfloat16(w1);
}

// ---------- conv: per-sample implicit GEMM with MFMA ----------
// block = 256 thr (4 waves); tile = 128 pixels (4 rows x 32 cols) x 128 oc
__global__ __launch_bounds__(256) void conv_kernel(
    const __hip_bfloat16* __restrict__ xn, const __hip_bfloat16* __restrict__ Wt,
    float* __restrict__ out) {
  __shared__ __align__(16) char smem[37632];
  unsigned short* xt = (unsigned short*)smem;            // [6][34][32] bf16 (13056 B)
  unsigned short* wt = (unsigned short*)(smem + 13056);  // [3][128][32] bf16 (24576 B)
  float (*cbuf)[129] = (float (*)[129])smem;             // [64][129] f32 (33024 B, aliased)

  int wc = blockIdx.x;       // 0..2
  int hr = blockIdx.y;       // 0..23
  int b  = blockIdx.z;       // 0..31
  int h0 = hr * 4, w0 = wc * 32;
  int tid = threadIdx.x;
  int lane = tid & 63, wid = tid >> 6;
  int wm0 = (wid >> 1) * 64, wn0 = (wid & 1) * 64;
  int l15 = lane & 15, lk = lane >> 4;

  f32x4 acc[4][4];
  #pragma unroll
  for (int i = 0; i < 4; i++)
    #pragma unroll
    for (int j = 0; j < 4; j++) acc[i][j] = (f32x4){0.f, 0.f, 0.f, 0.f};

  const __hip_bfloat16* xb = xn + (size_t)b * H_ * W_ * C_;
  const __hip_bfloat16* wb = Wt + (size_t)b * 9 * 128 * 128;

  for (int ic0 = 0; ic0 < 128; ic0 += 32) {
    for (int dy = 0; dy < 3; dy++) {
      __syncthreads();
      if (dy == 0) {
        // stage x halo tile [6][34][32ic]
        for (int idx = tid; idx < 816; idx += 256) {
          int cell = idx >> 2, part = idx & 3;
          int hh = cell / 34, ww = cell - hh * 34;
          int gh = h0 - 1 + hh, gw = w0 - 1 + ww;
          uint4 v = make_uint4(0, 0, 0, 0);
          if ((unsigned)gh < 96u && (unsigned)gw < 96u)
            v = *(const uint4*)(xb + ((size_t)(gh * 96 + gw)) * 128 + ic0 + part * 8);
          *(uint4*)(xt + (size_t)idx * 8) = v;
        }
      }
      // stage weights for taps dy*3+{0,1,2}: [3][128][32ic]
      for (int idx = tid; idx < 1536; idx += 256) {
        int dx = idx >> 9, rem = idx & 511;
        int oc = rem >> 2, part = rem & 3;
        const __hip_bfloat16* src =
            wb + ((size_t)((dy * 3 + dx) * 128 + oc)) * 128 + ic0 + part * 8;
        *(uint4*)(wt + (size_t)idx * 8) = *(const uint4*)src;
      }
      __syncthreads();
      #pragma unroll
      for (int dx = 0; dx < 3; dx++) {
        bf16x8 bfr[4], afr[4];
        #pragma unroll
        for (int j = 0; j < 4; j++) {
          int n = wn0 + j * 16 + l15;
          bfr[j] = *(const bf16x8*)(wt + ((size_t)(dx * 128 + n)) * 32 + lk * 8);
        }
        #pragma unroll
        for (int i = 0; i < 4; i++) {
          int m = wm0 + i * 16 + l15;
          int r = m >> 5, c = m & 31;
          afr[i] = *(const bf16x8*)(xt + ((size_t)((r + dy) * 34 + (c + dx))) * 32 + lk * 8);
        }
        #pragma unroll
        for (int i = 0; i < 4; i++)
          #pragma unroll
          for (int j = 0; j < 4; j++)
            acc[i][j] = __builtin_amdgcn_mfma_f32_16x16x32_bf16(afr[i], bfr[j], acc[i][j], 0, 0, 0);
      }
    }
  }

  // epilogue: transpose through LDS for contiguous f32 stores
  float* ob = out + (size_t)b * 128 * 96 * 96;
  #pragma unroll
  for (int half = 0; half < 2; half++) {
    __syncthreads();
    if (wm0 == half * 64) {
      #pragma unroll
      for (int i = 0; i < 4; i++)
        #pragma unroll
        for (int j = 0; j < 4; j++)
          #pragma unroll
          for (int r = 0; r < 4; r++) {
            int ml = i * 16 + lk * 4 + r;
            int n = wn0 + j * 16 + l15;
            cbuf[ml][n] = acc[i][j][r];
          }
    }
    __syncthreads();
    int w = tid & 31, pid = tid >> 5;
    for (int k = 0; k < 32; k++) {
      int task = pid * 32 + k;        // 0..255 = 128 oc x 2 rows
      int oc = task >> 1, rr = task & 1;
      int ml = rr * 32 + w;
      ob[((size_t)(oc * 96) + h0 + half * 2 + rr) * 96 + w0 + w] = cbuf[ml][oc];
    }
  }
}

extern "C" void kernel_launch(void* const* d_in, const int* in_sizes, int n_in,
                              void* d_out, int out_size, void* d_ws, size_t ws_size,
                              hipStream_t stream) {
  const float* x   = (const float*)d_in[0];
  const float* z   = (const float*)d_in[1];
  const float* bw  = (const float*)d_in[2];
  const float* gw  = (const float*)d_in[3];
  const float* pww = (const float*)d_in[4];
  const float* dww = (const float*)d_in[5];
  float* out = (float*)d_out;

  char* ws = (char*)d_ws;
  __hip_bfloat16* xn = (__hip_bfloat16*)ws;                       // 75,497,472 B
  __hip_bfloat16* Wt = (__hip_bfloat16*)(ws + 75497472);          //  9,437,184 B
  float* gate = (float*)(ws + 75497472 + 9437184);                // 32*128
  float* pwv  = gate + 32 * 128;                                  // 32*16384
  float* dwv  = pwv + 32 * 16384;                                 // 32*1152

  hipLaunchKernelGGL(prep_x_kernel,  dim3(4, 96, 32), dim3(256), 0, stream, x, xn);
  hipLaunchKernelGGL(prep_gpd_kernel, dim3(69, 1, 1), dim3(256), 0, stream,
                     z, gw, pww, dww, gate, pwv, dwv);
  hipLaunchKernelGGL(prep_w_kernel,  dim3(9216, 1, 1), dim3(256), 0, stream,
                     bw, gate, pwv, dwv, Wt);
  hipLaunchKernelGGL(conv_kernel,    dim3(3, 24, 32), dim3(256), 0, stream, xn, Wt, out);
}

// Round 2
// 198.572 us; speedup vs baseline: 1.3476x; 1.3476x over previous
//
#include <hip/hip_runtime.h>
#include <hip/hip_bf16.h>

#define B_ 32
#define C_ 128
#define H_ 96
#define W_ 96

typedef __bf16 bf16x8 __attribute__((ext_vector_type(8)));
typedef float f32x4 __attribute__((ext_vector_type(4)));

// row-pair XOR swizzle: logical (row n of 64B, 16B-chunk k) -> byte offset
__device__ __forceinline__ int swz(int n, int k) {
  int pair = n >> 1;
  int s = (((n & 1) << 2) | k) ^ (pair & 7);
  return (pair << 7) + (s << 4);
}

__device__ __forceinline__ void load_lds16(const void* g, void* l) {
  __builtin_amdgcn_global_load_lds((const __attribute__((address_space(1))) void*)g,
                                   (__attribute__((address_space(3))) void*)l, 16, 0, 0);
}

// ---------- prep_x: f32 NCHW -> bf16 [b][grp4][h][w][32ic] ----------
__global__ __launch_bounds__(512) void prep_x_kernel(const float* __restrict__ x,
                                                     __hip_bfloat16* __restrict__ xn) {
  __shared__ float tile[128][97];
  int h = blockIdx.x;   // 0..95
  int b = blockIdx.y;   // 0..31
  const float* src = x + (size_t)b * 128 * 9216 + h * 96;
  for (int f = threadIdx.x; f < 3072; f += 512) {   // 128 ic x 24 float4
    int ic = f / 24, w4 = f - ic * 24;
    float4 v = *(const float4*)(src + (size_t)ic * 9216 + w4 * 4);
    tile[ic][w4 * 4 + 0] = v.x; tile[ic][w4 * 4 + 1] = v.y;
    tile[ic][w4 * 4 + 2] = v.z; tile[ic][w4 * 4 + 3] = v.w;
  }
  __syncthreads();
  __hip_bfloat16* dst = xn + ((size_t)(b * 4) * 9216 + h * 96) * 32;
  for (int o = threadIdx.x; o < 6144; o += 512) {   // ushort2 units
    int grp = o / 1536, rem = o - grp * 1536;
    int w = rem >> 4, icp = rem & 15;
    float a0 = tile[grp * 32 + icp * 2][w];
    float a1 = tile[grp * 32 + icp * 2 + 1][w];
    __hip_bfloat162 pk = {__float2bfloat16(a0), __float2bfloat16(a1)};
    *(__hip_bfloat162*)(dst + (size_t)grp * 294912 + w * 32 + icp * 2) = pk;
  }
}

// ---------- prep_gpd: gate/pw/dw projections of z ----------
__global__ __launch_bounds__(256) void prep_gpd_kernel(
    const float* __restrict__ z, const float* __restrict__ gw,
    const float* __restrict__ pww, const float* __restrict__ dww,
    float* __restrict__ gate, float* __restrict__ pwv, float* __restrict__ dwv) {
  __shared__ float zs[32 * 64];
  for (int i = threadIdx.x; i < 32 * 64; i += 256) zs[i] = z[i];
  __syncthreads();
  int j = blockIdx.x * 256 + threadIdx.x;   // 0..17663
  const float* wrow; float* outp; int stride;
  if (j < 16384)             { wrow = pww + (size_t)j * 64;            outp = pwv + j;            stride = 16384; }
  else if (j < 16384 + 1152) { int jj = j - 16384; wrow = dww + (size_t)jj * 64; outp = dwv + jj; stride = 1152; }
  else                       { int jj = j - 17536; wrow = gw  + (size_t)jj * 64; outp = gate + jj; stride = 128; }
  float wr[64];
  #pragma unroll
  for (int i = 0; i < 16; i++) {
    float4 v = ((const float4*)wrow)[i];
    wr[4*i] = v.x; wr[4*i+1] = v.y; wr[4*i+2] = v.z; wr[4*i+3] = v.w;
  }
  for (int b = 0; b < 32; b++) {
    float acc = 0.f;
    #pragma unroll
    for (int i = 0; i < 64; i++) acc += zs[b * 64 + i] * wr[i];
    outp[(size_t)b * stride] = acc;
  }
}

// ---------- prep_w: merged weights -> Wt[b][grp4][tap9][oc128][32ic] bf16 ----------
__global__ __launch_bounds__(256) void prep_w_kernel(
    const float* __restrict__ base, const float* __restrict__ gate,
    const float* __restrict__ pwv, const float* __restrict__ dwv,
    __hip_bfloat16* __restrict__ Wt) {
  int gid = blockIdx.x * 256 + threadIdx.x;   // one thread = 2 consecutive ic
  int ic2  = gid & 63;  int rest  = gid >> 6;
  int oc   = rest & 127; int rest2 = rest >> 7;
  int t = rest2 % 9; int b = rest2 / 9;
  int ic = ic2 * 2;
  float g = gate[b * 128 + oc];
  float d = dwv[b * 1152 + oc * 9 + t];
  const float* pwp = pwv + (size_t)b * 16384 + oc * 128 + ic;
  const float* bp  = base + ((size_t)(oc * 128 + ic)) * 9 + t;
  float w0 = bp[0] * g + pwp[0] * d;
  float w1 = bp[9] * g + pwp[1] * d;
  int grp = ic >> 5, icL = ic & 31;
  __hip_bfloat16* o = Wt + ((((size_t)(b * 4 + grp) * 9 + t) * 128 + oc) * 32 + icL);
  o[0] = __float2bfloat16(w0);
  o[1] = __float2bfloat16(w1);
}

// ---------- conv: per-sample implicit GEMM, 256px x 128oc per block ----------
__global__ __launch_bounds__(512) void conv_kernel(
    const __hip_bfloat16* __restrict__ xn, const __hip_bfloat16* __restrict__ Wt,
    float* __restrict__ out) {
  __shared__ __align__(16) char smem[46336];
  char* xt = smem;              // 340 rows x 64B, swizzled (21760 B)
  char* wt = smem + 21760;      // 384 rows x 64B, swizzled (24576 B)

  int wc = blockIdx.x;          // 0..2
  int hr = blockIdx.y;          // 0..11
  int b  = blockIdx.z;          // 0..31
  int h0 = hr * 8, w0 = wc * 32;
  int tid = threadIdx.x;
  int lane = tid & 63, wid = tid >> 6;
  int wm0 = (wid >> 1) * 64, wn0 = (wid & 1) * 64;
  int l15 = lane & 15, lk = lane >> 4;

  // per-lane pre-swizzled global source offsets for the weight stage
  int woff[3];
  #pragma unroll
  for (int j = 0; j < 3; j++) {
    int p = (wid * 3 + j) * 64 + lane;      // linear 16B slot in LDS
    int pair = p >> 3, sp = p & 7;
    int s = sp ^ (pair & 7);
    int n = (pair << 1) | (s >> 2);
    int k = s & 3;
    woff[j] = n * 32 + k * 8;               // element offset in [3dx][128oc][32ic]
  }

  f32x4 acc[4][4];
  #pragma unroll
  for (int i = 0; i < 4; i++)
    #pragma unroll
    for (int j = 0; j < 4; j++) acc[i][j] = (f32x4){0.f, 0.f, 0.f, 0.f};

  for (int grp = 0; grp < 4; grp++) {
    const __hip_bfloat16* xbg = xn + (size_t)(b * 4 + grp) * 294912;
    const __hip_bfloat16* wbg = Wt + (size_t)(b * 4 + grp) * 36864;
    #pragma unroll
    for (int dy = 0; dy < 3; dy++) {
      __syncthreads();
      if (dy == 0) {
        // stage x halo tile: 340 rows ([10h][34w]) x 32 ic, swizzled reg-staging
        for (int idx = tid; idx < 1360; idx += 512) {
          int n = idx >> 2, k = idx & 3;
          int hh = n / 34, ww = n - hh * 34;
          int gh = h0 - 1 + hh, gw = w0 - 1 + ww;
          uint4 v = make_uint4(0, 0, 0, 0);
          if ((unsigned)gh < 96u && (unsigned)gw < 96u)
            v = *(const uint4*)(xbg + ((size_t)(gh * 96 + gw)) * 32 + k * 8);
          *(uint4*)(xt + swz(n, k)) = v;
        }
      }
      // async-stage weights [3dx][128oc][32ic]: linear LDS dest, swizzled source
      const __hip_bfloat16* wsrc = wbg + dy * 12288;
      #pragma unroll
      for (int j = 0; j < 3; j++)
        load_lds16(wsrc + woff[j], wt + ((wid * 3 + j) << 10));
      __syncthreads();

      #pragma unroll
      for (int dx = 0; dx < 3; dx++) {
        bf16x8 bfr[4], afr[4];
        #pragma unroll
        for (int j = 0; j < 4; j++) {
          int n = dx * 128 + wn0 + j * 16 + l15;
          bfr[j] = *(const bf16x8*)(wt + swz(n, lk));
        }
        #pragma unroll
        for (int i = 0; i < 4; i++) {
          int r = (wm0 >> 5) + (i >> 1) + dy;
          int c = ((i & 1) << 4) + l15 + dx;
          afr[i] = *(const bf16x8*)(xt + swz(r * 34 + c, lk));
        }
        #pragma unroll
        for (int i = 0; i < 4; i++)
          #pragma unroll
          for (int j = 0; j < 4; j++)
            acc[i][j] = __builtin_amdgcn_mfma_f32_16x16x32_bf16(afr[i], bfr[j], acc[i][j], 0, 0, 0);
      }
    }
  }

  // direct epilogue: each lane's f32x4 is 4 consecutive w at fixed (oc,h)
  float* ob = out + (size_t)b * 128 * 9216;
  #pragma unroll
  for (int i = 0; i < 4; i++) {
    int m0 = wm0 + i * 16;
    int hrow = h0 + (m0 >> 5);
    int wcol = w0 + (m0 & 31) + lk * 4;
    #pragma unroll
    for (int j = 0; j < 4; j++) {
      int oc = wn0 + j * 16 + l15;
      *(f32x4*)(ob + (size_t)oc * 9216 + hrow * 96 + wcol) = acc[i][j];
    }
  }
}

extern "C" void kernel_launch(void* const* d_in, const int* in_sizes, int n_in,
                              void* d_out, int out_size, void* d_ws, size_t ws_size,
                              hipStream_t stream) {
  const float* x   = (const float*)d_in[0];
  const float* z   = (const float*)d_in[1];
  const float* bw  = (const float*)d_in[2];
  const float* gw  = (const float*)d_in[3];
  const float* pww = (const float*)d_in[4];
  const float* dww = (const float*)d_in[5];
  float* out = (float*)d_out;

  char* ws = (char*)d_ws;
  __hip_bfloat16* xn = (__hip_bfloat16*)ws;                       // 75,497,472 B
  __hip_bfloat16* Wt = (__hip_bfloat16*)(ws + 75497472);          //  9,437,184 B
  float* gate = (float*)(ws + 75497472 + 9437184);                // 32*128
  float* pwv  = gate + 32 * 128;                                  // 32*16384
  float* dwv  = pwv + 32 * 16384;                                 // 32*1152

  hipLaunchKernelGGL(prep_x_kernel,  dim3(96, 32), dim3(512), 0, stream, x, xn);
  hipLaunchKernelGGL(prep_gpd_kernel, dim3(69, 1, 1), dim3(256), 0, stream,
                     z, gw, pww, dww, gate, pwv, dwv);
  hipLaunchKernelGGL(prep_w_kernel,  dim3(9216, 1, 1), dim3(256), 0, stream,
                     bw, gate, pwv, dwv, Wt);
  hipLaunchKernelGGL(conv_kernel,    dim3(3, 12, 32), dim3(512), 0, stream, xn, Wt, out);
}